// Round 9
// baseline (584.438 us; speedup 1.0000x reference)
//
#include <hip/hip_runtime.h>
#include <hip/hip_bf16.h>

// SAICNet: encoder LSTM (T=20, N=131072, E=32, H=64) via split-bf16 MFMA
// (7 terms: e*Wih + hhi*WhhH + hlo*WhhH + hhi*WhhL per K-half), double-buffered
// X, fused register pooling; decoder LSTM (T=30, S=4096, H=64) fp32 VALU.
// This round = EXACT round-4 kernel (passed, 376us, absmax 2.441e-4) with a
// single delta: XSTR 168 -> 172 (bank-conflict fix, proven correct in R5/R7).

typedef short short8 __attribute__((ext_vector_type(8)));
typedef float f32x4  __attribute__((ext_vector_type(4)));

__device__ __forceinline__ float rcp_(float x) { return __builtin_amdgcn_rcpf(x); }
__device__ __forceinline__ float sigmoid_(float x) { return rcp_(1.0f + __expf(-x)); }
__device__ __forceinline__ float tanh_(float x) {
    float e = __expf(-2.0f * fabsf(x));             // in (0,1], overflow-free
    float t = (1.0f - e) * rcp_(1.0f + e);
    return copysignf(t, x);
}
__device__ __forceinline__ short bf16rne_(float v) {
    unsigned u = __builtin_bit_cast(unsigned, v);
    u += 0x7FFF + ((u >> 16) & 1);
    return (short)(u >> 16);
}
__device__ __forceinline__ short bf16tr_(float v) {
    return (short)(__builtin_bit_cast(unsigned, v) >> 16);
}
__device__ __forceinline__ float b2f_(short s) {
    return __builtin_bit_cast(float, ((unsigned)(unsigned short)s) << 16);
}
__device__ __forceinline__ void split_(float w, short& h, short& l) {
    h = bf16tr_(w);
    l = bf16rne_(w - b2f_(h));
}

#define XSTR 172   // shorts/row: [emb 0..31 | h_hi 32..95 | h_lo 96..159 | pad]
// 86-dword stride: h-write l4-groups (drow=4 -> dbank=24) cover all 32 banks;
// b128 read starts cover 16 distinct banks (2-way, free).

// ---------------------------------------------------------------------------
// Encoder + pooling. 256 threads = 4 waves; block = 64 agents (2 scenes).
// Wave p owns gate cols {64g + 16p + l15 : g=0..3} for ALL 64 agents.
// Weights in VGPRs (80 regs): Bih RNE-bf16, Bhh split hi/lo (drop hlo*Wlo).
// X double-buffered in LDS -> ONE barrier per step. c fp32 in registers.
// A-frags loaded upfront (5 b128) -> max ILP across the 28-MFMA phase.
// MFMA 16x16x32 bf16: A row=l&15, k=(l>>4)*8+i; D col=l&15, row=(l>>4)*4+reg.
// ---------------------------------------------------------------------------
__global__ __launch_bounds__(256, 3) void enc_pool_kernel(
    const float* __restrict__ hist,      // [T,N,2]
    const float* __restrict__ hist_pos,  // [N,2]
    const float* __restrict__ W_ie,      // [2,32]
    const float* __restrict__ b_ie,      // [32]
    const float* __restrict__ Wih,       // [32,256]
    const float* __restrict__ Whh,       // [64,256]
    const float* __restrict__ bih,       // [256]
    const float* __restrict__ bhh,       // [256]
    const float* __restrict__ Wse,       // [2,64]
    const float* __restrict__ bse,       // [64]
    const float* __restrict__ Wmp,       // [128,64]
    const float* __restrict__ bmp,       // [64]
    float* __restrict__ encO,            // [S,128] (ws)
    int N, int T)
{
    __shared__ __align__(16) short sX[2][64 * XSTR];  // 44032 B
    __shared__ float sIE[96];    // W_ie(64)+b_ie(32)
    __shared__ float sWse[192];  // Wse(128)+bse(64)
    __shared__ float sTgt[128];  // exact fp32 h of scene-first agents

    const int tid = threadIdx.x;
    const int l15 = tid & 15;
    const int l4  = (tid & 63) >> 4;
    const int p   = tid >> 6;           // wave id = col-tile owner
    const int n0  = blockIdx.x << 6;    // first agent of block
    const int jcol = (p << 4) + l15;    // h column this lane owns

    // ---- W fragments into registers ----
    short8 Bih[4];                  // emb k-tile, RNE bf16, per gate n
    short8 BhhH[2][4], BhhL[2][4];  // h k-tiles, split hi/lo, per gate n
    float bias[4];
#pragma unroll
    for (int n = 0; n < 4; ++n) {
        int c = (n << 6) + jcol;
        short8 bi;
#pragma unroll
        for (int i = 0; i < 8; ++i)
            bi[i] = bf16rne_(Wih[(l4 * 8 + i) * 256 + c]);
        Bih[n] = bi;
#pragma unroll
        for (int kt = 0; kt < 2; ++kt) {
            short8 ch, cl;
#pragma unroll
            for (int i = 0; i < 8; ++i) {
                short hh, ll; split_(Whh[(kt * 32 + l4 * 8 + i) * 256 + c], hh, ll);
                ch[i] = hh; cl[i] = ll;
            }
            BhhH[kt][n] = ch; BhhL[kt][n] = cl;
        }
        bias[n] = bih[c] + bhh[c];
    }

    // ---- zero buf0, stage small tables ----
    for (int i = tid; i < 64 * XSTR / 2; i += 256) ((int*)sX[0])[i] = 0;
    if (tid < 64)       sIE[tid] = W_ie[tid];
    else if (tid < 96)  sIE[tid] = b_ie[tid - 64];
    if (tid < 128)      sWse[tid] = Wse[tid];
    else if (tid < 192) sWse[tid] = bse[tid - 128];
    __syncthreads();

    const float2* hist2 = (const float2*)hist;
    const int ag = tid >> 2;          // agent this thread embeds (0..63)
    const int eb = (tid & 3) << 3;    // its 8 emb dims

    auto emb_write = [&](int t) {
        float2 xy = hist2[(size_t)t * N + n0 + ag];
        short8 ev;
#pragma unroll
        for (int q = 0; q < 8; ++q) {
            int e = eb + q;
            float v = fmaf(xy.x, sIE[e], fmaf(xy.y, sIE[32 + e], sIE[64 + e]));
            ev[q] = bf16rne_(fmaxf(v, 0.0f));
        }
        *(short8*)(sX[t & 1] + ag * XSTR + eb) = ev;
    };
    emb_write(0);
    __syncthreads();

    float cst[4][4];
#pragma unroll
    for (int m = 0; m < 4; ++m)
#pragma unroll
        for (int r = 0; r < 4; ++r) cst[m][r] = 0.0f;

    for (int t = 0; t < T; ++t) {
        const short* bR = sX[t & 1];
        short* bW = sX[(t + 1) & 1];
#pragma unroll
        for (int m = 0; m < 4; ++m) {
            const short* row = bR + ((m << 4) + l15) * XSTR + l4 * 8;
            short8 aE  = *(const short8*)(row);
            short8 aH0 = *(const short8*)(row + 32);
            short8 aH1 = *(const short8*)(row + 64);
            short8 aL0 = *(const short8*)(row + 96);
            short8 aL1 = *(const short8*)(row + 128);
            f32x4 acc[4];
#pragma unroll
            for (int n = 0; n < 4; ++n)
                acc[n] = (f32x4){bias[n], bias[n], bias[n], bias[n]};
#pragma unroll
            for (int n = 0; n < 4; ++n) {
                acc[n] = __builtin_amdgcn_mfma_f32_16x16x32_bf16(aE,  Bih[n],     acc[n], 0, 0, 0);
                acc[n] = __builtin_amdgcn_mfma_f32_16x16x32_bf16(aH0, BhhH[0][n], acc[n], 0, 0, 0);
                acc[n] = __builtin_amdgcn_mfma_f32_16x16x32_bf16(aL0, BhhH[0][n], acc[n], 0, 0, 0);
                acc[n] = __builtin_amdgcn_mfma_f32_16x16x32_bf16(aH0, BhhL[0][n], acc[n], 0, 0, 0);
                acc[n] = __builtin_amdgcn_mfma_f32_16x16x32_bf16(aH1, BhhH[1][n], acc[n], 0, 0, 0);
                acc[n] = __builtin_amdgcn_mfma_f32_16x16x32_bf16(aL1, BhhH[1][n], acc[n], 0, 0, 0);
                acc[n] = __builtin_amdgcn_mfma_f32_16x16x32_bf16(aH1, BhhL[1][n], acc[n], 0, 0, 0);
            }
#pragma unroll
            for (int r = 0; r < 4; ++r) {
                float i_ = sigmoid_(acc[0][r]);
                float f_ = sigmoid_(acc[1][r]);
                float g_ = tanh_(acc[2][r]);
                float o_ = sigmoid_(acc[3][r]);
                cst[m][r] = fmaf(f_, cst[m][r], i_ * g_);
                float h = o_ * tanh_(cst[m][r]);
                short hh = bf16tr_(h);
                short hl = bf16rne_(h - b2f_(hh));
                int rw = (m << 4) + (l4 << 2) + r;
                bW[rw * XSTR + 32 + jcol] = hh;
                bW[rw * XSTR + 96 + jcol] = hl;
                if (t == T - 1 && l4 == 0 && (m & 1) == 0 && r == 0)
                    sTgt[(m >> 1) * 64 + jcol] = h;   // exact scene-first h
            }
        }
        if (t + 1 < T) emb_write(t + 1);
        __syncthreads();
    }

    // ---- social pooling: rel into dead buffer, Wmp in regs, MFMA ----
    short* rb = sX[(T + 1) & 1];      // buffer NOT holding final h
    const short* hb = sX[T & 1];      // final h (hi+lo)
    {
        const float2* pos2 = (const float2*)hist_pos;
        float2 pa = pos2[n0 + ag];
        float2 pb = pos2[n0 + (ag & 32)];   // scene-first agent (P=32)
        float px = pa.x - pb.x, py = pa.y - pb.y;
        int ebq = (tid & 3) << 4;
        short8 r0v, r1v;
#pragma unroll
        for (int q = 0; q < 8; ++q) {
            int e = ebq + q;
            float v = fmaf(px, sWse[e], fmaf(py, sWse[64 + e], sWse[128 + e]));
            r0v[q] = bf16rne_(fmaxf(v, 0.0f));
        }
#pragma unroll
        for (int q = 0; q < 8; ++q) {
            int e = ebq + 8 + q;
            float v = fmaf(px, sWse[e], fmaf(py, sWse[64 + e], sWse[128 + e]));
            r1v[q] = bf16rne_(fmaxf(v, 0.0f));
        }
        *(short8*)(rb + ag * XSTR + ebq)     = r0v;
        *(short8*)(rb + ag * XSTR + ebq + 8) = r1v;
    }
    // Wmp fragments: rows kt*32.. (k<64: h, k>=64: rel), col = jcol
    short8 BmH[4], BmL[4];
#pragma unroll
    for (int kt = 0; kt < 4; ++kt) {
        short8 bh, bl;
#pragma unroll
        for (int i = 0; i < 8; ++i) {
            short hh, ll; split_(Wmp[(kt * 32 + l4 * 8 + i) * 64 + jcol], hh, ll);
            bh[i] = hh; bl[i] = ll;
        }
        BmH[kt] = bh; BmL[kt] = bl;
    }
    float bmpv = bmp[jcol];
    __syncthreads();

    float smax0 = -3.4e38f, smax1 = -3.4e38f;
#pragma unroll
    for (int m = 0; m < 4; ++m) {
        const short* row  = hb + ((m << 4) + l15) * XSTR + l4 * 8;
        const short* rrow = rb + ((m << 4) + l15) * XSTR + l4 * 8;
        short8 h0 = *(const short8*)(row + 32);
        short8 h1 = *(const short8*)(row + 64);
        short8 q0 = *(const short8*)(row + 96);
        short8 q1 = *(const short8*)(row + 128);
        short8 r0 = *(const short8*)(rrow);
        short8 r1 = *(const short8*)(rrow + 32);
        f32x4 pc = (f32x4){bmpv, bmpv, bmpv, bmpv};
        pc = __builtin_amdgcn_mfma_f32_16x16x32_bf16(h0, BmH[0], pc, 0, 0, 0);
        pc = __builtin_amdgcn_mfma_f32_16x16x32_bf16(q0, BmH[0], pc, 0, 0, 0);
        pc = __builtin_amdgcn_mfma_f32_16x16x32_bf16(h0, BmL[0], pc, 0, 0, 0);
        pc = __builtin_amdgcn_mfma_f32_16x16x32_bf16(h1, BmH[1], pc, 0, 0, 0);
        pc = __builtin_amdgcn_mfma_f32_16x16x32_bf16(q1, BmH[1], pc, 0, 0, 0);
        pc = __builtin_amdgcn_mfma_f32_16x16x32_bf16(h1, BmL[1], pc, 0, 0, 0);
        pc = __builtin_amdgcn_mfma_f32_16x16x32_bf16(r0, BmH[2], pc, 0, 0, 0);
        pc = __builtin_amdgcn_mfma_f32_16x16x32_bf16(r0, BmL[2], pc, 0, 0, 0);
        pc = __builtin_amdgcn_mfma_f32_16x16x32_bf16(r1, BmH[3], pc, 0, 0, 0);
        pc = __builtin_amdgcn_mfma_f32_16x16x32_bf16(r1, BmL[3], pc, 0, 0, 0);
        float mx = fmaxf(fmaxf(pc[0], pc[1]), fmaxf(pc[2], pc[3]));
        mx = fmaxf(mx, 0.0f);   // relu(max) == max(relu)
        if (m < 2) smax0 = fmaxf(smax0, mx); else smax1 = fmaxf(smax1, mx);
    }
    smax0 = fmaxf(smax0, __shfl_xor(smax0, 16));
    smax0 = fmaxf(smax0, __shfl_xor(smax0, 32));
    smax1 = fmaxf(smax1, __shfl_xor(smax1, 16));
    smax1 = fmaxf(smax1, __shfl_xor(smax1, 32));
    if (l4 == 0) {
        int sg = blockIdx.x << 1;
        encO[sg * 128 + jcol]      = smax0;
        encO[sg * 128 + 64 + jcol] = sTgt[jcol];
    } else if (l4 == 1) {
        int sg = (blockIdx.x << 1) + 1;
        encO[sg * 128 + jcol]      = smax1;
        encO[sg * 128 + 64 + jcol] = sTgt[64 + jcol];
    }
}

// ---------------------------------------------------------------------------
// Decoder: WG = 256 threads = 4 waves = 4 scenes.
// ---------------------------------------------------------------------------
__global__ __launch_bounds__(256, 2) void dec_kernel(
    const float* __restrict__ enc,    // [S,128] (ws)
    const float* __restrict__ Wih_d,  // [128,256]
    const float* __restrict__ Whh_d,  // [64,256]
    const float* __restrict__ bih_d,  // [256]
    const float* __restrict__ bhh_d,  // [256]
    const float* __restrict__ Wop,    // [64,2]
    const float* __restrict__ bop,    // [2]
    float* __restrict__ out,          // [TOUT,S,2]
    int S, int TOUT)
{
    __shared__ __align__(16) float sWh[16384];   // [k64][j64][G4]
    __shared__ __align__(16) float sHd[256];     // [w4][j64]

    const int tid = threadIdx.x;
    const int j = tid & 63;
    const int w = tid >> 6;
    const int s = (blockIdx.x << 2) + w;

    for (int idx = tid; idx < 64 * 256; idx += 256) {
        int k = idx >> 8, col = idx & 255;
        sWh[((k << 6) | (col & 63)) * 4 + (col >> 6)] = Whh_d[idx];
    }
    sHd[tid] = 0.0f;

    float gx0 = bih_d[j]       + bhh_d[j];
    float gx1 = bih_d[64 + j]  + bhh_d[64 + j];
    float gx2 = bih_d[128 + j] + bhh_d[128 + j];
    float gx3 = bih_d[192 + j] + bhh_d[192 + j];
    for (int k = 0; k < 128; ++k) {
        float ev = enc[s * 128 + k];
        const float* col = Wih_d + k * 256;
        gx0 = fmaf(ev, col[j], gx0);
        gx1 = fmaf(ev, col[64 + j], gx1);
        gx2 = fmaf(ev, col[128 + j], gx2);
        gx3 = fmaf(ev, col[192 + j], gx3);
    }
    float wop0 = Wop[j * 2], wop1 = Wop[j * 2 + 1];
    float bop0 = bop[0], bop1 = bop[1];

    __syncthreads();

    const float4* Wh4 = reinterpret_cast<const float4*>(sWh);
    const float4* H4  = reinterpret_cast<const float4*>(sHd);

    float c = 0.0f;
    for (int t = 0; t < TOUT; ++t) {
        float g0 = gx0, g1 = gx1, g2 = gx2, g3 = gx3;
#pragma unroll 4
        for (int kq = 0; kq < 16; ++kq) {
            float4 hv = H4[(w << 4) + kq];
            float4 w0 = Wh4[((kq * 4 + 0) << 6) + j];
            float4 w1 = Wh4[((kq * 4 + 1) << 6) + j];
            float4 w2 = Wh4[((kq * 4 + 2) << 6) + j];
            float4 w3 = Wh4[((kq * 4 + 3) << 6) + j];
            g0 += hv.x * w0.x + hv.y * w1.x + hv.z * w2.x + hv.w * w3.x;
            g1 += hv.x * w0.y + hv.y * w1.y + hv.z * w2.y + hv.w * w3.y;
            g2 += hv.x * w0.z + hv.y * w1.z + hv.z * w2.z + hv.w * w3.z;
            g3 += hv.x * w0.w + hv.y * w1.w + hv.z * w2.w + hv.w * w3.w;
        }
        float i_ = sigmoid_(g0);
        float f_ = sigmoid_(g1);
        float gg = tanh_(g2);
        float o_ = sigmoid_(g3);
        c = fmaf(f_, c, i_ * gg);
        float h = o_ * tanh_(c);

        float r0 = h * wop0, r1 = h * wop1;
#pragma unroll
        for (int off = 32; off > 0; off >>= 1) {
            r0 += __shfl_xor(r0, off);
            r1 += __shfl_xor(r1, off);
        }
        if (j == 0) {
            float* op = out + ((size_t)t * S + s) * 2;
            op[0] = r0 + bop0;
            op[1] = r1 + bop1;
        }
        sHd[(w << 6) + j] = h;
    }
}

extern "C" void kernel_launch(void* const* d_in, const int* in_sizes, int n_in,
                              void* d_out, int out_size, void* d_ws, size_t ws_size,
                              hipStream_t stream) {
    (void)n_in; (void)ws_size;
    const float* hist     = (const float*)d_in[0];
    const float* hist_pos = (const float*)d_in[1];
    const float* W_ie     = (const float*)d_in[2];
    const float* b_ie     = (const float*)d_in[3];
    const float* Wih_e    = (const float*)d_in[4];
    const float* Whh_e    = (const float*)d_in[5];
    const float* bih_e    = (const float*)d_in[6];
    const float* bhh_e    = (const float*)d_in[7];
    const float* Wse      = (const float*)d_in[8];
    const float* bse      = (const float*)d_in[9];
    const float* Wmp      = (const float*)d_in[10];
    const float* bmp      = (const float*)d_in[11];
    const float* Wih_d    = (const float*)d_in[12];
    const float* Whh_d    = (const float*)d_in[13];
    const float* bih_d    = (const float*)d_in[14];
    const float* bhh_d    = (const float*)d_in[15];
    const float* Wop      = (const float*)d_in[16];
    const float* bop      = (const float*)d_in[17];

    const int N = in_sizes[1] / 2;
    const int T = in_sizes[0] / (N * 2);
    const int S = in_sizes[18] - 1;
    const int TOUT = out_size / (S * 2);

    float* enc = (float*)d_ws;   // [S,128] = 2 MB

    enc_pool_kernel<<<dim3(N / 64), dim3(256), 0, stream>>>(
        hist, hist_pos, W_ie, b_ie, Wih_e, Whh_e, bih_e, bhh_e,
        Wse, bse, Wmp, bmp, enc, N, T);

    dec_kernel<<<dim3(S / 4), dim3(256), 0, stream>>>(
        enc, Wih_d, Whh_d, bih_d, bhh_d, Wop, bop, (float*)d_out, S, TOUT);
}

// Round 10
// 496.701 us; speedup vs baseline: 1.1766x; 1.1766x over previous
//
#include <hip/hip_runtime.h>
#include <hip/hip_bf16.h>

// SAICNet encoder: barrier-free M-split LSTM. Wave = 1 scene (32 agents),
// computes all 256 gate cols via bf16 MFMA; weights as shared LDS B-frags
// (staged once); h transposed D->A through per-wave LDS scratch (intra-wave,
// no barriers in the T-loop). 7-term split-bf16 numerics (proven 2.441e-4).
// Decoder unchanged (proven).

typedef short short8 __attribute__((ext_vector_type(8)));
typedef float f32x4  __attribute__((ext_vector_type(4)));

__device__ __forceinline__ float rcp_(float x) { return __builtin_amdgcn_rcpf(x); }
__device__ __forceinline__ float sigmoid_(float x) { return rcp_(1.0f + __expf(-x)); }
__device__ __forceinline__ float tanh_(float x) {
    float e = __expf(-2.0f * fabsf(x));             // in (0,1], overflow-free
    float t = (1.0f - e) * rcp_(1.0f + e);
    return copysignf(t, x);
}
__device__ __forceinline__ short bf16rne_(float v) {
    unsigned u = __builtin_bit_cast(unsigned, v);
    u += 0x7FFF + ((u >> 16) & 1);
    return (short)(u >> 16);
}
__device__ __forceinline__ short bf16tr_(float v) {
    return (short)(__builtin_bit_cast(unsigned, v) >> 16);
}
__device__ __forceinline__ float b2f_(short s) {
    return __builtin_bit_cast(float, ((unsigned)(unsigned short)s) << 16);
}
__device__ __forceinline__ void split_(float w, short& h, short& l) {
    h = bf16tr_(w);
    l = bf16rne_(w - b2f_(h));
}
#define MFMA_ __builtin_amdgcn_mfma_f32_16x16x32_bf16

#define HROW 68      // u32 per agent row in h-scratch (16B-aligned rows; 2-way-free writes)

// ---------------------------------------------------------------------------
// 512 threads = 8 waves; block = 256 agents = 8 scenes; wave w = scene w.
// B-frags in LDS: set s in {0:Wih, 1:WhhH(k0..31), 2:WhhH(k32..63),
// 3:WhhL(k0..31), 4:WhhL(k32..63)} x 16 n-tiles x 64 lanes x short8.
// Frag mappings (m89-verified): A lane: row=l&15, k=(l>>4)*8+i;
// B lane: col=l&15, k=(l>>4)*8+i; D: col=l&15, row=(l>>4)*4+reg.
// ---------------------------------------------------------------------------
__global__ __launch_bounds__(512, 2) void enc_pool_kernel(
    const float* __restrict__ hist,      // [T,N,2]
    const float* __restrict__ hist_pos,  // [N,2]
    const float* __restrict__ W_ie,      // [2,32]
    const float* __restrict__ b_ie,      // [32]
    const float* __restrict__ Wih,       // [32,256]
    const float* __restrict__ Whh,       // [64,256]
    const float* __restrict__ bih,       // [256]
    const float* __restrict__ bhh,       // [256]
    const float* __restrict__ Wse,       // [2,64]
    const float* __restrict__ bse,       // [64]
    const float* __restrict__ Wmp,       // [128,64]
    const float* __restrict__ bmp,       // [64]
    float* __restrict__ encO,            // [S,128] (ws)
    int N, int T)
{
    __shared__ __align__(16) short    sB[40960];   // 80 KB: B-frags (pool: Wmp frags)
    __shared__ __align__(16) unsigned sH[8 * 32 * HROW];  // 68 KB: per-wave h scratch

    const int tid  = threadIdx.x;
    const int lane = tid & 63;
    const int l15  = lane & 15;
    const int l4   = lane >> 4;
    const int w    = tid >> 6;
    const int n0w  = (blockIdx.x << 8) + (w << 5);   // wave's first agent (scene start)

    // ---- stage LSTM B-frags (once, cooperative) ----
    for (int slot = tid; slot < 5120; slot += 512) {
        int s   = slot >> 10;
        int rem = slot & 1023;
        int lam = rem & 63;
        int k0  = (lam >> 4) << 3;
        int c   = ((rem >> 6) << 4) + (lam & 15);
        short8 v;
        if (s == 0) {
#pragma unroll
            for (int i = 0; i < 8; ++i)
                v[i] = bf16rne_(Wih[(k0 + i) * 256 + c]);
        } else {
            int kbase = (s == 2 || s == 4) ? 32 : 0;
            bool lo = (s >= 3);
#pragma unroll
            for (int i = 0; i < 8; ++i) {
                short hh, ll; split_(Whh[(kbase + k0 + i) * 256 + c], hh, ll);
                v[i] = lo ? ll : hh;
            }
        }
        *(short8*)(sB + ((size_t)slot << 3)) = v;
    }

    // ---- per-lane constants ----
    float wie0[8], wie1[8], bie[8];
#pragma unroll
    for (int i = 0; i < 8; ++i) {
        wie0[i] = W_ie[(l4 << 3) + i];
        wie1[i] = W_ie[32 + (l4 << 3) + i];
        bie[i]  = b_ie[(l4 << 3) + i];
    }
    float bias[4][4];   // [q][g]
#pragma unroll
    for (int q = 0; q < 4; ++q)
#pragma unroll
        for (int g = 0; g < 4; ++g) {
            int c = (g << 6) + (q << 4) + l15;
            bias[q][g] = bih[c] + bhh[c];
        }

    __syncthreads();   // B-frags visible

    const float2* hist2 = (const float2*)hist;
    unsigned* myH = sH + w * (32 * HROW);
    const short8* B8 = (const short8*)sB;

    float2 xyc0 = hist2[n0w + l15];
    float2 xyc1 = hist2[n0w + 16 + l15];

    float cst[2][4][4];
#pragma unroll
    for (int m = 0; m < 2; ++m)
#pragma unroll
        for (int q = 0; q < 4; ++q)
#pragma unroll
            for (int r = 0; r < 4; ++r) cst[m][q][r] = 0.0f;
    float tgtv[4] = {0.f, 0.f, 0.f, 0.f};

    for (int t = 0; t < T; ++t) {
        float2 xyn0, xyn1;
        if (t + 1 < T) {
            xyn0 = hist2[(size_t)(t + 1) * N + n0w + l15];
            xyn1 = hist2[(size_t)(t + 1) * N + n0w + 16 + l15];
        }
        // emb A-frags in-register (agent = 16m + l15; e = l4*8+i)
        short8 aE0, aE1;
#pragma unroll
        for (int i = 0; i < 8; ++i) {
            float v0 = fmaf(xyc0.x, wie0[i], fmaf(xyc0.y, wie1[i], bie[i]));
            float v1 = fmaf(xyc1.x, wie0[i], fmaf(xyc1.y, wie1[i], bie[i]));
            aE0[i] = bf16rne_(fmaxf(v0, 0.0f));
            aE1[i] = bf16rne_(fmaxf(v1, 0.0f));
        }
        // h A-frags from own scratch (packed hh|hl u32)
        short8 aH[2][2], aL[2][2];
        if (t > 0) {
#pragma unroll
            for (int m = 0; m < 2; ++m) {
                const unsigned* rp = myH + ((m << 4) + l15) * HROW + (l4 << 3);
#pragma unroll
                for (int kt = 0; kt < 2; ++kt) {
                    int4 u0 = *(const int4*)(rp + kt * 32);
                    int4 u1 = *(const int4*)(rp + kt * 32 + 4);
                    short8 hi, lo;
#pragma unroll
                    for (int i = 0; i < 4; ++i) {
                        hi[i]     = (short)(u0[i] & 0xFFFF);
                        lo[i]     = (short)((unsigned)u0[i] >> 16);
                        hi[4 + i] = (short)(u1[i] & 0xFFFF);
                        lo[4 + i] = (short)((unsigned)u1[i] >> 16);
                    }
                    aH[m][kt] = hi; aL[m][kt] = lo;
                }
            }
        }
#pragma unroll
        for (int q = 0; q < 4; ++q) {
            f32x4 acc[2][4];
#pragma unroll
            for (int g = 0; g < 4; ++g) {
                float b = bias[q][g];
                acc[0][g] = (f32x4){b, b, b, b};
                acc[1][g] = (f32x4){b, b, b, b};
            }
#pragma unroll
            for (int g = 0; g < 4; ++g) {
                int n = (g << 2) + q;
                short8 b0 = B8[(0 * 16 + n) * 64 + lane];
                acc[0][g] = MFMA_(aE0, b0, acc[0][g], 0, 0, 0);
                acc[1][g] = MFMA_(aE1, b0, acc[1][g], 0, 0, 0);
                if (t > 0) {
                    short8 bH0 = B8[(1 * 16 + n) * 64 + lane];
                    acc[0][g] = MFMA_(aH[0][0], bH0, acc[0][g], 0, 0, 0);
                    acc[1][g] = MFMA_(aH[1][0], bH0, acc[1][g], 0, 0, 0);
                    acc[0][g] = MFMA_(aL[0][0], bH0, acc[0][g], 0, 0, 0);
                    acc[1][g] = MFMA_(aL[1][0], bH0, acc[1][g], 0, 0, 0);
                    short8 bL0 = B8[(3 * 16 + n) * 64 + lane];
                    acc[0][g] = MFMA_(aH[0][0], bL0, acc[0][g], 0, 0, 0);
                    acc[1][g] = MFMA_(aH[1][0], bL0, acc[1][g], 0, 0, 0);
                    short8 bH1 = B8[(2 * 16 + n) * 64 + lane];
                    acc[0][g] = MFMA_(aH[0][1], bH1, acc[0][g], 0, 0, 0);
                    acc[1][g] = MFMA_(aH[1][1], bH1, acc[1][g], 0, 0, 0);
                    acc[0][g] = MFMA_(aL[0][1], bH1, acc[0][g], 0, 0, 0);
                    acc[1][g] = MFMA_(aL[1][1], bH1, acc[1][g], 0, 0, 0);
                    short8 bL1 = B8[(4 * 16 + n) * 64 + lane];
                    acc[0][g] = MFMA_(aH[0][1], bL1, acc[0][g], 0, 0, 0);
                    acc[1][g] = MFMA_(aH[1][1], bL1, acc[1][g], 0, 0, 0);
                }
            }
            // cell update for cols j = 16q + l15, agents 16m + l4*4 + r
#pragma unroll
            for (int m = 0; m < 2; ++m)
#pragma unroll
                for (int r = 0; r < 4; ++r) {
                    float i_ = sigmoid_(acc[m][0][r]);
                    float f_ = sigmoid_(acc[m][1][r]);
                    float g_ = tanh_(acc[m][2][r]);
                    float o_ = sigmoid_(acc[m][3][r]);
                    cst[m][q][r] = fmaf(f_, cst[m][q][r], i_ * g_);
                    float h = o_ * tanh_(cst[m][q][r]);
                    short hh = bf16tr_(h);
                    short hl = bf16rne_(h - b2f_(hh));
                    myH[((m << 4) + (l4 << 2) + r) * HROW + (q << 4) + l15] =
                        (unsigned)(unsigned short)hh | ((unsigned)(unsigned short)hl << 16);
                    if (t == T - 1 && m == 0 && l4 == 0 && r == 0)
                        tgtv[q] = h;   // exact fp32 h of scene-first agent
                }
        }
        xyc0 = xyn0; xyc1 = xyn1;
    }

    __syncthreads();   // all waves done reading LSTM B-frags

    // ---- stage Wmp frags: set s = kt*2 + (0 hi | 1 lo), kt 0..3, n 0..3 ----
    for (int slot = tid; slot < 2048; slot += 512) {
        int s   = slot >> 8;
        int rem = slot & 255;
        int lam = rem & 63;
        int k0  = (lam >> 4) << 3;
        int c   = ((rem >> 6) << 4) + (lam & 15);
        int kt  = s >> 1;
        bool lo = s & 1;
        short8 v;
#pragma unroll
        for (int i = 0; i < 8; ++i) {
            short hh, ll; split_(Wmp[(kt * 32 + k0 + i) * 64 + c], hh, ll);
            v[i] = lo ? ll : hh;
        }
        *(short8*)(sB + ((size_t)slot << 3)) = v;
    }
    // rel A-frags in-register (single RNE bf16, like emb)
    const float2* pos2 = (const float2*)hist_pos;
    float2 pb  = pos2[n0w];
    float2 pa0 = pos2[n0w + l15];
    float2 pa1 = pos2[n0w + 16 + l15];
    float px0 = pa0.x - pb.x, py0 = pa0.y - pb.y;
    float px1 = pa1.x - pb.x, py1 = pa1.y - pb.y;
    short8 aR[2][2];
#pragma unroll
    for (int kt = 0; kt < 2; ++kt) {
        int e0 = (kt << 5) + (l4 << 3);
#pragma unroll
        for (int i = 0; i < 8; ++i) {
            float ws0 = Wse[e0 + i], ws1 = Wse[64 + e0 + i], bs = bse[e0 + i];
            float v0 = fmaf(px0, ws0, fmaf(py0, ws1, bs));
            float v1 = fmaf(px1, ws0, fmaf(py1, ws1, bs));
            aR[0][kt][i] = bf16rne_(fmaxf(v0, 0.0f));
            aR[1][kt][i] = bf16rne_(fmaxf(v1, 0.0f));
        }
    }
    float bmpv[4];
#pragma unroll
    for (int n = 0; n < 4; ++n) bmpv[n] = bmp[(n << 4) + l15];
    // final h A-frags (re-read: regs hold t=T-2's h)
    short8 fH[2][2], fL[2][2];
#pragma unroll
    for (int m = 0; m < 2; ++m) {
        const unsigned* rp = myH + ((m << 4) + l15) * HROW + (l4 << 3);
#pragma unroll
        for (int kt = 0; kt < 2; ++kt) {
            int4 u0 = *(const int4*)(rp + kt * 32);
            int4 u1 = *(const int4*)(rp + kt * 32 + 4);
            short8 hi, lo;
#pragma unroll
            for (int i = 0; i < 4; ++i) {
                hi[i]     = (short)(u0[i] & 0xFFFF);
                lo[i]     = (short)((unsigned)u0[i] >> 16);
                hi[4 + i] = (short)(u1[i] & 0xFFFF);
                lo[4 + i] = (short)((unsigned)u1[i] >> 16);
            }
            fH[m][kt] = hi; fL[m][kt] = lo;
        }
    }
    __syncthreads();   // Wmp frags visible

    float sm[4];
#pragma unroll
    for (int n = 0; n < 4; ++n) {
        f32x4 p0 = (f32x4){bmpv[n], bmpv[n], bmpv[n], bmpv[n]};
        f32x4 p1 = p0;
        short8 b;
        b = B8[(0 * 4 + n) * 64 + lane];   // kt0 hi
        p0 = MFMA_(fH[0][0], b, p0, 0, 0, 0); p1 = MFMA_(fH[1][0], b, p1, 0, 0, 0);
        p0 = MFMA_(fL[0][0], b, p0, 0, 0, 0); p1 = MFMA_(fL[1][0], b, p1, 0, 0, 0);
        b = B8[(1 * 4 + n) * 64 + lane];   // kt0 lo
        p0 = MFMA_(fH[0][0], b, p0, 0, 0, 0); p1 = MFMA_(fH[1][0], b, p1, 0, 0, 0);
        b = B8[(2 * 4 + n) * 64 + lane];   // kt1 hi
        p0 = MFMA_(fH[0][1], b, p0, 0, 0, 0); p1 = MFMA_(fH[1][1], b, p1, 0, 0, 0);
        p0 = MFMA_(fL[0][1], b, p0, 0, 0, 0); p1 = MFMA_(fL[1][1], b, p1, 0, 0, 0);
        b = B8[(3 * 4 + n) * 64 + lane];   // kt1 lo
        p0 = MFMA_(fH[0][1], b, p0, 0, 0, 0); p1 = MFMA_(fH[1][1], b, p1, 0, 0, 0);
        b = B8[(4 * 4 + n) * 64 + lane];   // rel kt2 hi
        p0 = MFMA_(aR[0][0], b, p0, 0, 0, 0); p1 = MFMA_(aR[1][0], b, p1, 0, 0, 0);
        b = B8[(5 * 4 + n) * 64 + lane];   // rel kt2 lo
        p0 = MFMA_(aR[0][0], b, p0, 0, 0, 0); p1 = MFMA_(aR[1][0], b, p1, 0, 0, 0);
        b = B8[(6 * 4 + n) * 64 + lane];   // rel kt3 hi
        p0 = MFMA_(aR[0][1], b, p0, 0, 0, 0); p1 = MFMA_(aR[1][1], b, p1, 0, 0, 0);
        b = B8[(7 * 4 + n) * 64 + lane];   // rel kt3 lo
        p0 = MFMA_(aR[0][1], b, p0, 0, 0, 0); p1 = MFMA_(aR[1][1], b, p1, 0, 0, 0);
        float mx = fmaxf(fmaxf(fmaxf(p0[0], p0[1]), fmaxf(p0[2], p0[3])),
                         fmaxf(fmaxf(p1[0], p1[1]), fmaxf(p1[2], p1[3])));
        mx = fmaxf(mx, 0.0f);                       // relu(max) == max(relu)
        mx = fmaxf(mx, __shfl_xor(mx, 16));
        mx = fmaxf(mx, __shfl_xor(mx, 32));
        sm[n] = mx;
    }
    int sg = (blockIdx.x << 3) + w;
    if (l4 == 0) {
#pragma unroll
        for (int n = 0; n < 4; ++n) encO[sg * 128 + (n << 4) + l15] = sm[n];
#pragma unroll
        for (int q = 0; q < 4; ++q) encO[sg * 128 + 64 + (q << 4) + l15] = tgtv[q];
    }
}

// ---------------------------------------------------------------------------
// Decoder: WG = 256 threads = 4 waves = 4 scenes (proven).
// ---------------------------------------------------------------------------
__global__ __launch_bounds__(256, 2) void dec_kernel(
    const float* __restrict__ enc,    // [S,128] (ws)
    const float* __restrict__ Wih_d,  // [128,256]
    const float* __restrict__ Whh_d,  // [64,256]
    const float* __restrict__ bih_d,  // [256]
    const float* __restrict__ bhh_d,  // [256]
    const float* __restrict__ Wop,    // [64,2]
    const float* __restrict__ bop,    // [2]
    float* __restrict__ out,          // [TOUT,S,2]
    int S, int TOUT)
{
    __shared__ __align__(16) float sWh[16384];   // [k64][j64][G4]
    __shared__ __align__(16) float sHd[256];     // [w4][j64]

    const int tid = threadIdx.x;
    const int j = tid & 63;
    const int w = tid >> 6;
    const int s = (blockIdx.x << 2) + w;

    for (int idx = tid; idx < 64 * 256; idx += 256) {
        int k = idx >> 8, col = idx & 255;
        sWh[((k << 6) | (col & 63)) * 4 + (col >> 6)] = Whh_d[idx];
    }
    sHd[tid] = 0.0f;

    float gx0 = bih_d[j]       + bhh_d[j];
    float gx1 = bih_d[64 + j]  + bhh_d[64 + j];
    float gx2 = bih_d[128 + j] + bhh_d[128 + j];
    float gx3 = bih_d[192 + j] + bhh_d[192 + j];
    for (int k = 0; k < 128; ++k) {
        float ev = enc[s * 128 + k];
        const float* col = Wih_d + k * 256;
        gx0 = fmaf(ev, col[j], gx0);
        gx1 = fmaf(ev, col[64 + j], gx1);
        gx2 = fmaf(ev, col[128 + j], gx2);
        gx3 = fmaf(ev, col[192 + j], gx3);
    }
    float wop0 = Wop[j * 2], wop1 = Wop[j * 2 + 1];
    float bop0 = bop[0], bop1 = bop[1];

    __syncthreads();

    const float4* Wh4 = reinterpret_cast<const float4*>(sWh);
    const float4* H4  = reinterpret_cast<const float4*>(sHd);

    float c = 0.0f;
    for (int t = 0; t < TOUT; ++t) {
        float g0 = gx0, g1 = gx1, g2 = gx2, g3 = gx3;
#pragma unroll 4
        for (int kq = 0; kq < 16; ++kq) {
            float4 hv = H4[(w << 4) + kq];
            float4 w0 = Wh4[((kq * 4 + 0) << 6) + j];
            float4 w1 = Wh4[((kq * 4 + 1) << 6) + j];
            float4 w2 = Wh4[((kq * 4 + 2) << 6) + j];
            float4 w3 = Wh4[((kq * 4 + 3) << 6) + j];
            g0 += hv.x * w0.x + hv.y * w1.x + hv.z * w2.x + hv.w * w3.x;
            g1 += hv.x * w0.y + hv.y * w1.y + hv.z * w2.y + hv.w * w3.y;
            g2 += hv.x * w0.z + hv.y * w1.z + hv.z * w2.z + hv.w * w3.z;
            g3 += hv.x * w0.w + hv.y * w1.w + hv.z * w2.w + hv.w * w3.w;
        }
        float i_ = sigmoid_(g0);
        float f_ = sigmoid_(g1);
        float gg = tanh_(g2);
        float o_ = sigmoid_(g3);
        c = fmaf(f_, c, i_ * gg);
        float h = o_ * tanh_(c);

        float r0 = h * wop0, r1 = h * wop1;
#pragma unroll
        for (int off = 32; off > 0; off >>= 1) {
            r0 += __shfl_xor(r0, off);
            r1 += __shfl_xor(r1, off);
        }
        if (j == 0) {
            float* op = out + ((size_t)t * S + s) * 2;
            op[0] = r0 + bop0;
            op[1] = r1 + bop1;
        }
        sHd[(w << 6) + j] = h;
    }
}

extern "C" void kernel_launch(void* const* d_in, const int* in_sizes, int n_in,
                              void* d_out, int out_size, void* d_ws, size_t ws_size,
                              hipStream_t stream) {
    (void)n_in; (void)ws_size;
    const float* hist     = (const float*)d_in[0];
    const float* hist_pos = (const float*)d_in[1];
    const float* W_ie     = (const float*)d_in[2];
    const float* b_ie     = (const float*)d_in[3];
    const float* Wih_e    = (const float*)d_in[4];
    const float* Whh_e    = (const float*)d_in[5];
    const float* bih_e    = (const float*)d_in[6];
    const float* bhh_e    = (const float*)d_in[7];
    const float* Wse      = (const float*)d_in[8];
    const float* bse      = (const float*)d_in[9];
    const float* Wmp      = (const float*)d_in[10];
    const float* bmp      = (const float*)d_in[11];
    const float* Wih_d    = (const float*)d_in[12];
    const float* Whh_d    = (const float*)d_in[13];
    const float* bih_d    = (const float*)d_in[14];
    const float* bhh_d    = (const float*)d_in[15];
    const float* Wop      = (const float*)d_in[16];
    const float* bop      = (const float*)d_in[17];

    const int N = in_sizes[1] / 2;
    const int T = in_sizes[0] / (N * 2);
    const int S = in_sizes[18] - 1;
    const int TOUT = out_size / (S * 2);

    float* enc = (float*)d_ws;   // [S,128] = 2 MB

    enc_pool_kernel<<<dim3(N / 256), dim3(512), 0, stream>>>(
        hist, hist_pos, W_ie, b_ie, Wih_e, Whh_e, bih_e, bhh_e,
        Wse, bse, Wmp, bmp, enc, N, T);

    dec_kernel<<<dim3(S / 4), dim3(256), 0, stream>>>(
        enc, Wih_d, Whh_d, bih_d, bhh_d, Wop, bop, (float*)d_out, S, TOUT);
}

// Round 11
// 431.639 us; speedup vs baseline: 1.3540x; 1.1507x over previous
//
#include <hip/hip_runtime.h>
#include <hip/hip_bf16.h>

// SAICNet: encoder = the round-4 measured-best kernel (376us, absmax 2.441e-4),
// resubmitted byte-identical. Decoder re-blocked to 8 scenes / 512 threads for
// 4 waves/SIMD latency hiding (was 4 scenes / 256 threads).

typedef short short8 __attribute__((ext_vector_type(8)));
typedef float f32x4  __attribute__((ext_vector_type(4)));

__device__ __forceinline__ float rcp_(float x) { return __builtin_amdgcn_rcpf(x); }
__device__ __forceinline__ float sigmoid_(float x) { return rcp_(1.0f + __expf(-x)); }
__device__ __forceinline__ float tanh_(float x) {
    float e = __expf(-2.0f * fabsf(x));             // in (0,1], overflow-free
    float t = (1.0f - e) * rcp_(1.0f + e);
    return copysignf(t, x);
}
__device__ __forceinline__ short bf16rne_(float v) {
    unsigned u = __builtin_bit_cast(unsigned, v);
    u += 0x7FFF + ((u >> 16) & 1);
    return (short)(u >> 16);
}
__device__ __forceinline__ short bf16tr_(float v) {
    return (short)(__builtin_bit_cast(unsigned, v) >> 16);
}
__device__ __forceinline__ float b2f_(short s) {
    return __builtin_bit_cast(float, ((unsigned)(unsigned short)s) << 16);
}
__device__ __forceinline__ void split_(float w, short& h, short& l) {
    h = bf16tr_(w);
    l = bf16rne_(w - b2f_(h));
}

#define XSTR 168   // shorts/row: [emb 0..31 | h_hi 32..95 | h_lo 96..159 | pad 8]

// ---------------------------------------------------------------------------
// Encoder + pooling. 256 threads = 4 waves; block = 64 agents (2 scenes).
// Wave p owns gate cols {64g + 16p + l15 : g=0..3} for ALL 64 agents.
// Weights in VGPRs (80 regs): Bih RNE-bf16, Bhh split hi/lo (drop hlo*Wlo).
// X double-buffered in LDS -> ONE barrier per step. c fp32 in registers.
// A-frags loaded upfront (5 b128) -> max ILP across the 28-MFMA phase.
// MFMA 16x16x32 bf16: A row=l&15, k=(l>>4)*8+i; D col=l&15, row=(l>>4)*4+reg.
// ---------------------------------------------------------------------------
__global__ __launch_bounds__(256, 3) void enc_pool_kernel(
    const float* __restrict__ hist,      // [T,N,2]
    const float* __restrict__ hist_pos,  // [N,2]
    const float* __restrict__ W_ie,      // [2,32]
    const float* __restrict__ b_ie,      // [32]
    const float* __restrict__ Wih,       // [32,256]
    const float* __restrict__ Whh,       // [64,256]
    const float* __restrict__ bih,       // [256]
    const float* __restrict__ bhh,       // [256]
    const float* __restrict__ Wse,       // [2,64]
    const float* __restrict__ bse,       // [64]
    const float* __restrict__ Wmp,       // [128,64]
    const float* __restrict__ bmp,       // [64]
    float* __restrict__ encO,            // [S,128] (ws)
    int N, int T)
{
    __shared__ __align__(16) short sX[2][64 * XSTR];  // 43008 B
    __shared__ float sIE[96];    // W_ie(64)+b_ie(32)
    __shared__ float sWse[192];  // Wse(128)+bse(64)
    __shared__ float sTgt[128];  // exact fp32 h of scene-first agents

    const int tid = threadIdx.x;
    const int l15 = tid & 15;
    const int l4  = (tid & 63) >> 4;
    const int p   = tid >> 6;           // wave id = col-tile owner
    const int n0  = blockIdx.x << 6;    // first agent of block
    const int jcol = (p << 4) + l15;    // h column this lane owns

    // ---- W fragments into registers ----
    short8 Bih[4];                  // emb k-tile, RNE bf16, per gate n
    short8 BhhH[2][4], BhhL[2][4];  // h k-tiles, split hi/lo, per gate n
    float bias[4];
#pragma unroll
    for (int n = 0; n < 4; ++n) {
        int c = (n << 6) + jcol;
        short8 bi;
#pragma unroll
        for (int i = 0; i < 8; ++i)
            bi[i] = bf16rne_(Wih[(l4 * 8 + i) * 256 + c]);
        Bih[n] = bi;
#pragma unroll
        for (int kt = 0; kt < 2; ++kt) {
            short8 ch, cl;
#pragma unroll
            for (int i = 0; i < 8; ++i) {
                short hh, ll; split_(Whh[(kt * 32 + l4 * 8 + i) * 256 + c], hh, ll);
                ch[i] = hh; cl[i] = ll;
            }
            BhhH[kt][n] = ch; BhhL[kt][n] = cl;
        }
        bias[n] = bih[c] + bhh[c];
    }

    // ---- zero buf0, stage small tables ----
    for (int i = tid; i < 64 * XSTR / 2; i += 256) ((int*)sX[0])[i] = 0;
    if (tid < 64)       sIE[tid] = W_ie[tid];
    else if (tid < 96)  sIE[tid] = b_ie[tid - 64];
    if (tid < 128)      sWse[tid] = Wse[tid];
    else if (tid < 192) sWse[tid] = bse[tid - 128];
    __syncthreads();

    const float2* hist2 = (const float2*)hist;
    const int ag = tid >> 2;          // agent this thread embeds (0..63)
    const int eb = (tid & 3) << 3;    // its 8 emb dims

    auto emb_write = [&](int t) {
        float2 xy = hist2[(size_t)t * N + n0 + ag];
        short8 ev;
#pragma unroll
        for (int q = 0; q < 8; ++q) {
            int e = eb + q;
            float v = fmaf(xy.x, sIE[e], fmaf(xy.y, sIE[32 + e], sIE[64 + e]));
            ev[q] = bf16rne_(fmaxf(v, 0.0f));
        }
        *(short8*)(sX[t & 1] + ag * XSTR + eb) = ev;
    };
    emb_write(0);
    __syncthreads();

    float cst[4][4];
#pragma unroll
    for (int m = 0; m < 4; ++m)
#pragma unroll
        for (int r = 0; r < 4; ++r) cst[m][r] = 0.0f;

    for (int t = 0; t < T; ++t) {
        const short* bR = sX[t & 1];
        short* bW = sX[(t + 1) & 1];
#pragma unroll
        for (int m = 0; m < 4; ++m) {
            const short* row = bR + ((m << 4) + l15) * XSTR + l4 * 8;
            short8 aE  = *(const short8*)(row);
            short8 aH0 = *(const short8*)(row + 32);
            short8 aH1 = *(const short8*)(row + 64);
            short8 aL0 = *(const short8*)(row + 96);
            short8 aL1 = *(const short8*)(row + 128);
            f32x4 acc[4];
#pragma unroll
            for (int n = 0; n < 4; ++n)
                acc[n] = (f32x4){bias[n], bias[n], bias[n], bias[n]};
#pragma unroll
            for (int n = 0; n < 4; ++n) {
                acc[n] = __builtin_amdgcn_mfma_f32_16x16x32_bf16(aE,  Bih[n],     acc[n], 0, 0, 0);
                acc[n] = __builtin_amdgcn_mfma_f32_16x16x32_bf16(aH0, BhhH[0][n], acc[n], 0, 0, 0);
                acc[n] = __builtin_amdgcn_mfma_f32_16x16x32_bf16(aL0, BhhH[0][n], acc[n], 0, 0, 0);
                acc[n] = __builtin_amdgcn_mfma_f32_16x16x32_bf16(aH0, BhhL[0][n], acc[n], 0, 0, 0);
                acc[n] = __builtin_amdgcn_mfma_f32_16x16x32_bf16(aH1, BhhH[1][n], acc[n], 0, 0, 0);
                acc[n] = __builtin_amdgcn_mfma_f32_16x16x32_bf16(aL1, BhhH[1][n], acc[n], 0, 0, 0);
                acc[n] = __builtin_amdgcn_mfma_f32_16x16x32_bf16(aH1, BhhL[1][n], acc[n], 0, 0, 0);
            }
#pragma unroll
            for (int r = 0; r < 4; ++r) {
                float i_ = sigmoid_(acc[0][r]);
                float f_ = sigmoid_(acc[1][r]);
                float g_ = tanh_(acc[2][r]);
                float o_ = sigmoid_(acc[3][r]);
                cst[m][r] = fmaf(f_, cst[m][r], i_ * g_);
                float h = o_ * tanh_(cst[m][r]);
                short hh = bf16tr_(h);
                short hl = bf16rne_(h - b2f_(hh));
                int rw = (m << 4) + (l4 << 2) + r;
                bW[rw * XSTR + 32 + jcol] = hh;
                bW[rw * XSTR + 96 + jcol] = hl;
                if (t == T - 1 && l4 == 0 && r == 0 && (m & 1) == 0)
                    sTgt[(m >> 1) * 64 + jcol] = h;   // exact scene-first h
            }
        }
        if (t + 1 < T) emb_write(t + 1);
        __syncthreads();
    }

    // ---- social pooling: rel into dead buffer, Wmp in regs, MFMA ----
    short* rb = sX[(T + 1) & 1];      // buffer NOT holding final h
    const short* hb = sX[T & 1];      // final h (hi+lo)
    {
        const float2* pos2 = (const float2*)hist_pos;
        float2 pa = pos2[n0 + ag];
        float2 pb = pos2[n0 + (ag & 32)];   // scene-first agent (P=32)
        float px = pa.x - pb.x, py = pa.y - pb.y;
        int ebq = (tid & 3) << 4;
        short8 r0v, r1v;
#pragma unroll
        for (int q = 0; q < 8; ++q) {
            int e = ebq + q;
            float v = fmaf(px, sWse[e], fmaf(py, sWse[64 + e], sWse[128 + e]));
            r0v[q] = bf16rne_(fmaxf(v, 0.0f));
        }
#pragma unroll
        for (int q = 0; q < 8; ++q) {
            int e = ebq + 8 + q;
            float v = fmaf(px, sWse[e], fmaf(py, sWse[64 + e], sWse[128 + e]));
            r1v[q] = bf16rne_(fmaxf(v, 0.0f));
        }
        *(short8*)(rb + ag * XSTR + ebq)     = r0v;
        *(short8*)(rb + ag * XSTR + ebq + 8) = r1v;
    }
    // Wmp fragments: rows kt*32.. (k<64: h, k>=64: rel), col = jcol
    short8 BmH[4], BmL[4];
#pragma unroll
    for (int kt = 0; kt < 4; ++kt) {
        short8 bh, bl;
#pragma unroll
        for (int i = 0; i < 8; ++i) {
            short hh, ll; split_(Wmp[(kt * 32 + l4 * 8 + i) * 64 + jcol], hh, ll);
            bh[i] = hh; bl[i] = ll;
        }
        BmH[kt] = bh; BmL[kt] = bl;
    }
    float bmpv = bmp[jcol];
    __syncthreads();

    float smax0 = -3.4e38f, smax1 = -3.4e38f;
#pragma unroll
    for (int m = 0; m < 4; ++m) {
        const short* row  = hb + ((m << 4) + l15) * XSTR + l4 * 8;
        const short* rrow = rb + ((m << 4) + l15) * XSTR + l4 * 8;
        short8 h0 = *(const short8*)(row + 32);
        short8 h1 = *(const short8*)(row + 64);
        short8 q0 = *(const short8*)(row + 96);
        short8 q1 = *(const short8*)(row + 128);
        short8 r0 = *(const short8*)(rrow);
        short8 r1 = *(const short8*)(rrow + 32);
        f32x4 pc = (f32x4){bmpv, bmpv, bmpv, bmpv};
        pc = __builtin_amdgcn_mfma_f32_16x16x32_bf16(h0, BmH[0], pc, 0, 0, 0);
        pc = __builtin_amdgcn_mfma_f32_16x16x32_bf16(q0, BmH[0], pc, 0, 0, 0);
        pc = __builtin_amdgcn_mfma_f32_16x16x32_bf16(h0, BmL[0], pc, 0, 0, 0);
        pc = __builtin_amdgcn_mfma_f32_16x16x32_bf16(h1, BmH[1], pc, 0, 0, 0);
        pc = __builtin_amdgcn_mfma_f32_16x16x32_bf16(q1, BmH[1], pc, 0, 0, 0);
        pc = __builtin_amdgcn_mfma_f32_16x16x32_bf16(h1, BmL[1], pc, 0, 0, 0);
        pc = __builtin_amdgcn_mfma_f32_16x16x32_bf16(r0, BmH[2], pc, 0, 0, 0);
        pc = __builtin_amdgcn_mfma_f32_16x16x32_bf16(r0, BmL[2], pc, 0, 0, 0);
        pc = __builtin_amdgcn_mfma_f32_16x16x32_bf16(r1, BmH[3], pc, 0, 0, 0);
        pc = __builtin_amdgcn_mfma_f32_16x16x32_bf16(r1, BmL[3], pc, 0, 0, 0);
        float mx = fmaxf(fmaxf(pc[0], pc[1]), fmaxf(pc[2], pc[3]));
        mx = fmaxf(mx, 0.0f);   // relu(max) == max(relu)
        if (m < 2) smax0 = fmaxf(smax0, mx); else smax1 = fmaxf(smax1, mx);
    }
    smax0 = fmaxf(smax0, __shfl_xor(smax0, 16));
    smax0 = fmaxf(smax0, __shfl_xor(smax0, 32));
    smax1 = fmaxf(smax1, __shfl_xor(smax1, 16));
    smax1 = fmaxf(smax1, __shfl_xor(smax1, 32));
    if (l4 == 0) {
        int sg = blockIdx.x << 1;
        encO[sg * 128 + jcol]      = smax0;
        encO[sg * 128 + 64 + jcol] = sTgt[jcol];
    } else if (l4 == 1) {
        int sg = (blockIdx.x << 1) + 1;
        encO[sg * 128 + jcol]      = smax1;
        encO[sg * 128 + 64 + jcol] = sTgt[64 + jcol];
    }
}

// ---------------------------------------------------------------------------
// Decoder: WG = 512 threads = 8 waves = 8 scenes. LDS 66.5 KB -> 2 blocks/CU
// = 16 waves/CU (4/SIMD); whole S resident in one round (512 blocks = 2/CU).
// Per-scene math identical to the proven 4-scene version.
// ---------------------------------------------------------------------------
__global__ __launch_bounds__(512, 2) void dec_kernel(
    const float* __restrict__ enc,    // [S,128] (ws)
    const float* __restrict__ Wih_d,  // [128,256]
    const float* __restrict__ Whh_d,  // [64,256]
    const float* __restrict__ bih_d,  // [256]
    const float* __restrict__ bhh_d,  // [256]
    const float* __restrict__ Wop,    // [64,2]
    const float* __restrict__ bop,    // [2]
    float* __restrict__ out,          // [TOUT,S,2]
    int S, int TOUT)
{
    __shared__ __align__(16) float sWh[16384];   // [k64][j64][G4]
    __shared__ __align__(16) float sHd[512];     // [w8][j64]

    const int tid = threadIdx.x;
    const int j = tid & 63;
    const int w = tid >> 6;
    const int s = (blockIdx.x << 3) + w;

    for (int idx = tid; idx < 64 * 256; idx += 512) {
        int k = idx >> 8, col = idx & 255;
        sWh[((k << 6) | (col & 63)) * 4 + (col >> 6)] = Whh_d[idx];
    }
    sHd[tid] = 0.0f;

    float gx0 = bih_d[j]       + bhh_d[j];
    float gx1 = bih_d[64 + j]  + bhh_d[64 + j];
    float gx2 = bih_d[128 + j] + bhh_d[128 + j];
    float gx3 = bih_d[192 + j] + bhh_d[192 + j];
    for (int k = 0; k < 128; ++k) {
        float ev = enc[s * 128 + k];
        const float* col = Wih_d + k * 256;
        gx0 = fmaf(ev, col[j], gx0);
        gx1 = fmaf(ev, col[64 + j], gx1);
        gx2 = fmaf(ev, col[128 + j], gx2);
        gx3 = fmaf(ev, col[192 + j], gx3);
    }
    float wop0 = Wop[j * 2], wop1 = Wop[j * 2 + 1];
    float bop0 = bop[0], bop1 = bop[1];

    __syncthreads();

    const float4* Wh4 = reinterpret_cast<const float4*>(sWh);
    const float4* H4  = reinterpret_cast<const float4*>(sHd);

    float c = 0.0f;
    for (int t = 0; t < TOUT; ++t) {
        float g0 = gx0, g1 = gx1, g2 = gx2, g3 = gx3;
#pragma unroll 4
        for (int kq = 0; kq < 16; ++kq) {
            float4 hv = H4[(w << 4) + kq];
            float4 w0 = Wh4[((kq * 4 + 0) << 6) + j];
            float4 w1 = Wh4[((kq * 4 + 1) << 6) + j];
            float4 w2 = Wh4[((kq * 4 + 2) << 6) + j];
            float4 w3 = Wh4[((kq * 4 + 3) << 6) + j];
            g0 += hv.x * w0.x + hv.y * w1.x + hv.z * w2.x + hv.w * w3.x;
            g1 += hv.x * w0.y + hv.y * w1.y + hv.z * w2.y + hv.w * w3.y;
            g2 += hv.x * w0.z + hv.y * w1.z + hv.z * w2.z + hv.w * w3.z;
            g3 += hv.x * w0.w + hv.y * w1.w + hv.z * w2.w + hv.w * w3.w;
        }
        float i_ = sigmoid_(g0);
        float f_ = sigmoid_(g1);
        float gg = tanh_(g2);
        float o_ = sigmoid_(g3);
        c = fmaf(f_, c, i_ * gg);
        float h = o_ * tanh_(c);

        float r0 = h * wop0, r1 = h * wop1;
#pragma unroll
        for (int off = 32; off > 0; off >>= 1) {
            r0 += __shfl_xor(r0, off);
            r1 += __shfl_xor(r1, off);
        }
        if (j == 0) {
            float* op = out + ((size_t)t * S + s) * 2;
            op[0] = r0 + bop0;
            op[1] = r1 + bop1;
        }
        sHd[(w << 6) + j] = h;   // own row; intra-wave ordering suffices
    }
}

extern "C" void kernel_launch(void* const* d_in, const int* in_sizes, int n_in,
                              void* d_out, int out_size, void* d_ws, size_t ws_size,
                              hipStream_t stream) {
    (void)n_in; (void)ws_size;
    const float* hist     = (const float*)d_in[0];
    const float* hist_pos = (const float*)d_in[1];
    const float* W_ie     = (const float*)d_in[2];
    const float* b_ie     = (const float*)d_in[3];
    const float* Wih_e    = (const float*)d_in[4];
    const float* Whh_e    = (const float*)d_in[5];
    const float* bih_e    = (const float*)d_in[6];
    const float* bhh_e    = (const float*)d_in[7];
    const float* Wse      = (const float*)d_in[8];
    const float* bse      = (const float*)d_in[9];
    const float* Wmp      = (const float*)d_in[10];
    const float* bmp      = (const float*)d_in[11];
    const float* Wih_d    = (const float*)d_in[12];
    const float* Whh_d    = (const float*)d_in[13];
    const float* bih_d    = (const float*)d_in[14];
    const float* bhh_d    = (const float*)d_in[15];
    const float* Wop      = (const float*)d_in[16];
    const float* bop      = (const float*)d_in[17];

    const int N = in_sizes[1] / 2;
    const int T = in_sizes[0] / (N * 2);
    const int S = in_sizes[18] - 1;
    const int TOUT = out_size / (S * 2);

    float* enc = (float*)d_ws;   // [S,128] = 2 MB

    enc_pool_kernel<<<dim3(N / 64), dim3(256), 0, stream>>>(
        hist, hist_pos, W_ie, b_ie, Wih_e, Whh_e, bih_e, bhh_e,
        Wse, bse, Wmp, bmp, enc, N, T);

    dec_kernel<<<dim3(S / 8), dim3(512), 0, stream>>>(
        enc, Wih_d, Whh_d, bih_d, bhh_d, Wop, bop, (float*)d_out, S, TOUT);
}